// Round 3
// baseline (88.008 us; speedup 1.0000x reference)
//
#include <hip/hip_runtime.h>

// Problem constants (from reference): BS=8, Q=500, NC=2, T=400
#define P_TOT  4000   // BS*Q
#define T_TOT  400
#define T_TILE 200    // targets per block (2 x-tiles, no tail)
#define PP     8      // preds per block
#define BD     256    // 4 waves

__global__ __launch_bounds__(BD, 3) void hm_cost_kernel(
    const float* __restrict__ logits,    // [P_TOT, 2]
    const float* __restrict__ kp,        // [P_TOT, 53]
    const int*   __restrict__ tgt_ids,   // [T_TOT]
    const float* __restrict__ tk,        // [T_TOT, 53]
    const int*   __restrict__ num_boxes, // [1]
    float*       __restrict__ out)       // [P_TOT, T_TOT]
{
    __shared__ float s_tk[T_TILE * 53];  // 42.4 KB -> 3 blocks/CU

    // ---- coalesced float4 staging of 200 contiguous target rows ----
    // tile byte offset = blockIdx.x * 42400, 16B-aligned; 10600 floats = 2650 float4
    {
        const float4* __restrict__ src4 =
            (const float4*)(tk + blockIdx.x * (T_TILE * 53));
        float4* dst4 = (float4*)s_tk;
#pragma unroll
        for (int i = threadIdx.x; i < (T_TILE * 53) / 4; i += BD)
            dst4[i] = src4[i];
    }
    __syncthreads();

    const int tl     = threadIdx.x;          // local target index
    const bool valid = (tl < T_TILE);
    const int tlc    = valid ? tl : (T_TILE - 1);
    const int tg     = blockIdx.x * T_TILE + tlc;  // global target

    const float nbinv = 1.0f / (float)(*num_boxes);

    // ---- pull this thread's target row from LDS into registers ----
    // lane stride 53 dwords: 53%32=21, gcd(21,32)=1 -> conflict-free
    const float* trow = &s_tk[tlc * 53];
    const float Cg0 = trow[0];
    const float Cg1 = trow[1];
    float Zg[34];
#pragma unroll
    for (int k = 0; k < 34; ++k) Zg[k] = trow[2 + k];
    float Vg[17];
    float sVg = 0.f;
#pragma unroll
    for (int j = 0; j < 17; ++j) {
        Vg[j] = trow[36 + j];
        sVg += Vg[j] * Vg[j];
    }
    const bool cls1 = (tgt_ids[tg] != 0);    // contiguous -> coalesced

    const int pbase = blockIdx.y * PP;

#pragma unroll 2
    for (int pi = 0; pi < PP; ++pi) {
        const int p = pbase + pi;            // uniform across block
        const float* __restrict__ prow = kp + p * 53;  // uniform -> broadcast/scalar

        // 2-class softmax, one exp: p0 = 1/(1+e^(l1-l0)), p1 = q*p0
        const float l0 = logits[2 * p];
        const float l1 = logits[2 * p + 1];
        const float q  = __expf(l1 - l0);
        const float p0 = 1.0f / (1.0f + q);
        const float prob = cls1 ? (q * p0) : p0;

        const float dc0 = prow[0] - Cg0;
        const float dc1 = prow[1] - Cg1;

        // fused 17-iter loop: offset L1 + abs L1 (share dz) + vis terms.
        // Vg in {0,1} >= 0, so |dz*v| == |dz|*v.
        float off = 0.f, ab = 0.f, vv = 0.f, sVp = 0.f;
#pragma unroll
        for (int j = 0; j < 17; ++j) {
            const float v   = Vg[j];
            const float dz0 = prow[2 + 2 * j]     - Zg[2 * j];
            const float dz1 = prow[3 + 2 * j]     - Zg[2 * j + 1];
            off += (fabsf(dz0) + fabsf(dz1)) * v;
            ab  += (fabsf(dz0 + dc0) + fabsf(dz1 + dc1)) * v;
            const float vp = prow[36 + j];
            vv  += vp * v;
            sVp += vp * vp;
        }

        const float viz = sVp - 2.f * vv + sVg;  // sum (Vp - Vg)^2
        const float ctr = dc0 * dc0 + dc1 * dc1;

        const float c = -prob
                      + (0.5f * off + 4.0f * ab + 0.2f * viz + 0.5f * ctr) * nbinv;

        if (valid) out[p * T_TOT + blockIdx.x * T_TILE + tl] = c;  // coalesced
    }
}

extern "C" void kernel_launch(void* const* d_in, const int* in_sizes, int n_in,
                              void* d_out, int out_size, void* d_ws, size_t ws_size,
                              hipStream_t stream) {
    const float* logits    = (const float*)d_in[0];  // pred_logits    [8,500,2]
    const float* kp        = (const float*)d_in[1];  // pred_keypoints [8,500,53]
    const int*   tgt_ids   = (const int*)  d_in[2];  // [400]
    const float* tk        = (const float*)d_in[3];  // tgt_keypoints  [400,53]
    const int*   num_boxes = (const int*)  d_in[4];  // scalar
    float*       out       = (float*)d_out;          // [8,500,400] fp32

    dim3 grid(T_TOT / T_TILE, P_TOT / PP);           // (2, 500)
    hm_cost_kernel<<<grid, BD, 0, stream>>>(logits, kp, tgt_ids, tk,
                                            num_boxes, out);
}

// Round 4
// 81.262 us; speedup vs baseline: 1.0830x; 1.0830x over previous
//
#include <hip/hip_runtime.h>

// Problem constants (from reference): BS=8, Q=500, NC=2, T=400
#define P_TOT   4000   // BS*Q
#define T_TOT   400
#define T_TILE  200    // targets per block (2 x-tiles, no tail)
#define PP      8      // preds per block
#define BD      256    // 4 waves
#define PSTRIDE 56     // padded pred row in LDS: 53 kp + l0 + l1 + pad (16B-aligned rows)

// compile-time float4-array element select (folds after full unroll)
#define PE(e) (((e) & 3) == 0 ? P[(e) >> 2].x : \
               ((e) & 3) == 1 ? P[(e) >> 2].y : \
               ((e) & 3) == 2 ? P[(e) >> 2].z : P[(e) >> 2].w)

__global__ __launch_bounds__(BD, 3) void hm_cost_kernel(
    const float* __restrict__ logits,    // [P_TOT, 2]
    const float* __restrict__ kp,        // [P_TOT, 53]
    const int*   __restrict__ tgt_ids,   // [T_TOT]
    const float* __restrict__ tk,        // [T_TOT, 53]
    const int*   __restrict__ num_boxes, // [1]
    float*       __restrict__ out)       // [P_TOT, T_TOT]
{
    __shared__ float s_tgt[T_TILE * 53];    // 42400 B, stride 53 == global layout
    __shared__ float s_pred[PP * PSTRIDE];  // 1792 B

    const int pbase = blockIdx.y * PP;

    // ---- stage target tile: straight contiguous float4 copy ----
    {
        const float4* __restrict__ src4 =
            (const float4*)(tk + blockIdx.x * (T_TILE * 53));
        float4* dst4 = (float4*)s_tgt;
        for (int i = threadIdx.x; i < (T_TILE * 53) / 4; i += BD)
            dst4[i] = src4[i];
    }
    // ---- stage 8 pred rows + logits into padded LDS rows ----
    for (int i = threadIdx.x; i < PP * 53 + 2 * PP; i += BD) {
        if (i < PP * 53) {
            const int row = i / 53;              // magic-mul div
            const int col = i - row * 53;
            s_pred[row * PSTRIDE + col] = kp[pbase * 53 + i];
        } else {
            const int j = i - PP * 53;           // 0..15
            const int row = j >> 1, c = j & 1;
            s_pred[row * PSTRIDE + 53 + c] = logits[(pbase + row) * 2 + c];
        }
    }
    __syncthreads();

    const int tl     = threadIdx.x;
    const bool valid = (tl < T_TILE);
    const int tlc    = valid ? tl : (T_TILE - 1);
    const int tg     = blockIdx.x * T_TILE + tlc;

    const float nbinv = 1.0f / (float)(*num_boxes);

    // ---- pin target row in registers (LDS b32, stride 53: conflict-free) ----
    const float* trow = &s_tgt[tlc * 53];
    const float Cg0 = trow[0];
    const float Cg1 = trow[1];
    float Zg[34];
#pragma unroll
    for (int k = 0; k < 34; ++k) Zg[k] = trow[2 + k];
    float Vg[17];
    float sVg = 0.f;
#pragma unroll
    for (int j = 0; j < 17; ++j) {
        Vg[j] = trow[36 + j];
        sVg += Vg[j] * Vg[j];
    }
    const bool cls1 = (tgt_ids[tg] != 0);        // coalesced, once

    const int obase = blockIdx.x * T_TILE + tl;

#pragma unroll 1
    for (int pi = 0; pi < PP; ++pi) {
        // pred row via 14 ds_read_b128, same-address broadcast (conflict-free)
        const float4* __restrict__ pr4 = (const float4*)&s_pred[pi * PSTRIDE];
        float4 P[14];
#pragma unroll
        for (int k = 0; k < 14; ++k) P[k] = pr4[k];

        // 2-class softmax, one exp: p0 = 1/(1+e^(l1-l0)), p1 = q*p0
        const float q  = __expf(PE(54) - PE(53));
        const float p0 = 1.0f / (1.0f + q);
        const float prob = cls1 ? (q * p0) : p0;

        const float dc0 = PE(0) - Cg0;
        const float dc1 = PE(1) - Cg1;

        // fused 17-iter loop: offset L1 + abs L1 (share dz) + vis terms.
        // Vg in {0,1} >= 0, so |dz*v| == |dz|*v.
        float off = 0.f, ab = 0.f, vv = 0.f, sVp = 0.f;
#pragma unroll
        for (int j = 0; j < 17; ++j) {
            const float v   = Vg[j];
            const float dz0 = PE(2 + 2 * j) - Zg[2 * j];
            const float dz1 = PE(3 + 2 * j) - Zg[2 * j + 1];
            off += (fabsf(dz0) + fabsf(dz1)) * v;
            ab  += (fabsf(dz0 + dc0) + fabsf(dz1 + dc1)) * v;
            const float vp = PE(36 + j);
            vv  += vp * v;
            sVp += vp * vp;
        }

        const float viz = sVp - 2.f * vv + sVg;  // sum (Vp - Vg)^2
        const float ctr = dc0 * dc0 + dc1 * dc1;

        const float c = -prob
                      + (0.5f * off + 4.0f * ab + 0.2f * viz + 0.5f * ctr) * nbinv;

        if (valid) out[(pbase + pi) * T_TOT + obase] = c;  // coalesced
    }
}

extern "C" void kernel_launch(void* const* d_in, const int* in_sizes, int n_in,
                              void* d_out, int out_size, void* d_ws, size_t ws_size,
                              hipStream_t stream) {
    const float* logits    = (const float*)d_in[0];  // pred_logits    [8,500,2]
    const float* kp        = (const float*)d_in[1];  // pred_keypoints [8,500,53]
    const int*   tgt_ids   = (const int*)  d_in[2];  // [400]
    const float* tk        = (const float*)d_in[3];  // tgt_keypoints  [400,53]
    const int*   num_boxes = (const int*)  d_in[4];  // scalar
    float*       out       = (float*)d_out;          // [8,500,400] fp32

    dim3 grid(T_TOT / T_TILE, P_TOT / PP);           // (2, 500)
    hm_cost_kernel<<<grid, BD, 0, stream>>>(logits, kp, tgt_ids, tk,
                                            num_boxes, out);
}

// Round 5
// 78.752 us; speedup vs baseline: 1.1175x; 1.0319x over previous
//
#include <hip/hip_runtime.h>

// Problem constants (from reference): BS=8, Q=500, NC=2, T=400
#define P_TOT 4000   // BS*Q
#define T_TOT 400
#define PP    8      // preds per block
#define BD    448    // 7 waves; covers all 400 targets, 10.7% lane waste

// NOTE (R4 post-mortem): dur_us is dominated by ~77-81 us of harness poison
// fills (2 x 268 MB at ~6.6 TB/s, i.e. at HBM roofline). Kernel contribution
// is ~5 us (VALU-issue floor) and below measurement noise. This is the
// best-measured variant (R2: 78.1 us); LDS-staging variants (R3/R4) were
// neutral-to-worse. Do not add complexity here without per-kernel counters.

__global__ __launch_bounds__(BD, 3) void hm_cost_kernel(
    const float* __restrict__ logits,    // [P_TOT, 2]
    const float* __restrict__ kp,        // [P_TOT, 53]
    const int*   __restrict__ tgt_ids,   // [T_TOT]
    const float* __restrict__ tk,        // [T_TOT, 53]
    const int*   __restrict__ num_boxes, // [1]
    float*       __restrict__ out)       // [P_TOT, T_TOT]
{
    const int t      = threadIdx.x;
    const bool valid = (t < T_TOT);
    const int tc     = valid ? t : (T_TOT - 1);   // clamp for safe loads

    const float nbinv = 1.0f / (float)(*num_boxes);

    // ---- pin this thread's target row in registers for the whole block ----
    const float* trow = tk + tc * 53;
    const float Cg0 = trow[0];
    const float Cg1 = trow[1];
    float Zg[34];
#pragma unroll
    for (int k = 0; k < 34; ++k) Zg[k] = trow[2 + k];
    float Vg[17];
    float sVg = 0.f;   // sum Vg^2 (hoisted out of pred loop)
#pragma unroll
    for (int j = 0; j < 17; ++j) {
        Vg[j] = trow[36 + j];
        sVg += Vg[j] * Vg[j];
    }
    const bool cls1 = (tgt_ids[tc] != 0);

    const int pbase = blockIdx.x * PP;

#pragma unroll 1
    for (int pi = 0; pi < PP; ++pi) {
        const int p = pbase + pi;                 // uniform across block
        const float* prow = kp + p * 53;          // uniform address

        // 2-class softmax with one exp: p0 = 1/(1+e^(l1-l0)), p1 = q*p0
        const float l0 = logits[2 * p];
        const float l1 = logits[2 * p + 1];
        const float q  = __expf(l1 - l0);
        const float p0 = 1.0f / (1.0f + q);
        const float prob = cls1 ? (q * p0) : p0;

        const float dc0 = prow[0] - Cg0;
        const float dc1 = prow[1] - Cg1;

        // fused 17-iter loop: offset L1, abs L1 (shares dz), vis cross-term.
        // Vg in {0,1} >= 0, so |dz*v| == |dz|*v.
        float off = 0.f, ab = 0.f, vv = 0.f, sVp = 0.f;
#pragma unroll
        for (int j = 0; j < 17; ++j) {
            const float v   = Vg[j];
            const float zp0 = prow[2 + 2 * j];
            const float zp1 = prow[3 + 2 * j];
            const float dz0 = zp0 - Zg[2 * j];
            const float dz1 = zp1 - Zg[2 * j + 1];
            off += (fabsf(dz0) + fabsf(dz1)) * v;
            ab  += (fabsf(dz0 + dc0) + fabsf(dz1 + dc1)) * v;
            const float vp = prow[36 + j];
            vv  += vp * v;
            sVp += vp * vp;
        }

        const float viz = sVp - 2.f * vv + sVg;   // sum (Vp - Vg)^2
        const float ctr = dc0 * dc0 + dc1 * dc1;

        const float c = -prob
                      + (0.5f * off + 4.0f * ab + 0.2f * viz + 0.5f * ctr) * nbinv;

        if (valid) out[p * T_TOT + t] = c;        // coalesced, t-contiguous
    }
}

extern "C" void kernel_launch(void* const* d_in, const int* in_sizes, int n_in,
                              void* d_out, int out_size, void* d_ws, size_t ws_size,
                              hipStream_t stream) {
    const float* logits    = (const float*)d_in[0];  // pred_logits    [8,500,2]
    const float* kp        = (const float*)d_in[1];  // pred_keypoints [8,500,53]
    const int*   tgt_ids   = (const int*)  d_in[2];  // [400]
    const float* tk        = (const float*)d_in[3];  // tgt_keypoints  [400,53]
    const int*   num_boxes = (const int*)  d_in[4];  // scalar
    float*       out       = (float*)d_out;          // [8,500,400] fp32

    hm_cost_kernel<<<P_TOT / PP, BD, 0, stream>>>(logits, kp, tgt_ids, tk,
                                                  num_boxes, out);
}